// Round 2
// baseline (12005.820 us; speedup 1.0000x reference)
//
#include <hip/hip_runtime.h>
#include <cstddef>
#include <cstdint>

typedef _Float16 half8 __attribute__((ext_vector_type(8)));
typedef float    floatx4 __attribute__((ext_vector_type(4)));

// ws layout (bytes)
#define HPRE_OFF   0u            // 8192*256 f32 = 8388608
#define SUM_OFF    8388608u      // 512 f32
#define PACK_OFF   8390656u
#define W1P_HALFS  163840        // 320 frags * 512
#define W2P_HALFS  327680        // 640 frags * 512
#define W3P_HALFS  81920         // 160 frags * 512
#define WO1P_HALFS 81920         // 160 frags * 512
#define WS_NEEDED  (PACK_OFF + (size_t)(W1P_HALFS+W2P_HALFS+W3P_HALFS+WO1P_HALFS)*2)

#define SWZ(row,f) ((f) ^ (((row)&7)<<3))   // xor-swizzle feat bits 3..5 by batch-row bits 0..2

// LDS float-offsets for staged constants
#define B1C   0
#define B2C   1280
#define B3C   2560
#define W1XC  2880
#define WO1XC 5440
#define BO1C  6720
#define NCONS 6976
#define SMEM_BYTES 152064   // S 40960 + H 81920 + cons 27904 + xq 1280

// ---------------- pack: f32 weights -> f16 MFMA A-fragment order ----------------
// A-frag for 16x16x32: lane holds A[m = mt*16 + (lane&15)][k = kk*32 + (lane>>4)*8 + j]
// A = W^T (m = out-feature, k = in-feature)
__global__ __launch_bounds__(256) void pack_kernel(
    const float* __restrict__ W1, const float* __restrict__ W2,
    const float* __restrict__ W3, const float* __restrict__ Wo1,
    _Float16* __restrict__ w1p, _Float16* __restrict__ w2p,
    _Float16* __restrict__ w3p, _Float16* __restrict__ wo1p,
    float* __restrict__ sums)
{
    int id = blockIdx.x * 256 + threadIdx.x;
    if (id < 512) sums[id] = 0.f;           // zero BN accumulators
    int f = id >> 6;
    int lane = id & 63;
    int q = lane >> 4, cl = lane & 15;
    if (f < 320) {                           // W1 state rows: frag (n*16+mt)*4+kk
        int kk = f & 3, mt = (f >> 2) & 15, n = f >> 6;
        #pragma unroll
        for (int j = 0; j < 8; j++)
            w1p[(size_t)f*512 + lane*8 + j] =
                (_Float16)W1[(size_t)(n*130 + 2 + kk*32 + q*8 + j)*256 + mt*16 + cl];
    } else if (f < 960) {                    // W2: frag (n*16+mt)*8+kk
        int g = f - 320;
        int kk = g & 7, mt = (g >> 3) & 15, n = g >> 7;
        #pragma unroll
        for (int j = 0; j < 8; j++)
            w2p[(size_t)g*512 + lane*8 + j] =
                (_Float16)W2[(size_t)(n*256 + kk*32 + q*8 + j)*256 + mt*16 + cl];
    } else if (f < 1120) {                   // W3: frag (n*4+mt)*8+kk
        int g = f - 960;
        int kk = g & 7, mt = (g >> 3) & 3, n = g >> 5;
        #pragma unroll
        for (int j = 0; j < 8; j++)
            w3p[(size_t)g*512 + lane*8 + j] =
                (_Float16)W3[(size_t)(n*256 + kk*32 + q*8 + j)*64 + mt*16 + cl];
    } else {                                 // Wo1 state rows: frag mt*10+kk
        int g = f - 1120;
        int kk = g % 10, mt = g / 10;
        #pragma unroll
        for (int j = 0; j < 8; j++)
            wo1p[(size_t)g*512 + lane*8 + j] =
                (_Float16)Wo1[(size_t)(5 + kk*32 + q*8 + j)*256 + mt*16 + cl];
    }
}

// ---------------- the 128-step scan: 1024 threads, weights register-resident ----------------
__global__ __launch_bounds__(1024, 4) void scan_kernel(
    const float* __restrict__ x,
    const float* __restrict__ W1, const float* __restrict__ b1,
    const float* __restrict__ b2, const float* __restrict__ b3,
    const float* __restrict__ Wo1, const float* __restrict__ bo1,
    const _Float16* __restrict__ w1p, const _Float16* __restrict__ w2p,
    const _Float16* __restrict__ w3p, const _Float16* __restrict__ wo1p,
    float* __restrict__ hpre)
{
    extern __shared__ char smem[];
    _Float16* S = (_Float16*)smem;               // 2 bufs * 5 nodes * 32 rows * 64 feats
    _Float16* H = S + 20480;                     // 5 nodes * 32 rows * 256 feats (H1, then H2 aliased)
    float* cons = (float*)(smem + 122880);       // 6976 floats
    float* xq   = (float*)(smem + 150784);       // 2 bufs * 5 nodes * 32 rows

    const int tid  = threadIdx.x;
    const int w    = tid >> 6;
    const int lane = tid & 63;
    const int quad = lane >> 4;
    const int cl   = lane & 15;
    const int b0   = blockIdx.x * 32;
    const bool isL2 = (w < 10);
    const int n2 = w >> 1, mh = w & 1;           // L2/L3 wave role
    const int n1 = (w >= 15) ? 4 : (w - 10);     // L1 wave role (clamped for wave 15)

    const int P0t[5] = {3,0,0,1,2};
    const int P1t[5] = {4,4,1,2,3};

    // ---- load resident weight fragments (once) ----
    half8 wf[64];
    half8 w3f[16];
    {
        const _Float16* wb = isL2
            ? (w2p + ((size_t)n2*128 + (size_t)mh*64)*512)
            : (w1p + (size_t)n1*64*512);
        #pragma unroll
        for (int i = 0; i < 64; i++)
            wf[i] = *(const half8*)(wb + (size_t)i*512 + lane*8);
        if (isL2) {
            const _Float16* wb3 = w3p + ((size_t)n2*32 + (size_t)mh*16)*512;
            #pragma unroll
            for (int i = 0; i < 16; i++)
                w3f[i] = *(const half8*)(wb3 + (size_t)i*512 + lane*8);
        }
    }

    // ---- stage constants, x_0, zero initial state ----
    for (int i = tid; i < NCONS; i += 1024) {
        float v;
        if      (i < 1280) v = b1[i];
        else if (i < 2560) v = b2[i-1280];
        else if (i < 2880) v = b3[i-2560];
        else if (i < 5440) { int j = i-2880; v = W1[(size_t)((j>>9)*130 + ((j>>8)&1))*256 + (j&255)]; }
        else if (i < 6720) { int j = i-5440; v = Wo1[(size_t)(j>>8)*256 + (j&255)]; }
        else               v = bo1[i-6720];
        cons[i] = v;
    }
    if (tid < 160) {
        int p = tid >> 5, r = tid & 31;
        xq[tid] = x[(size_t)(b0 + r)*640 + p*128 + 0];
    }
    for (int i = tid; i < 10240; i += 1024) S[i] = (_Float16)0.f;
    __syncthreads();

    int cur = 0;
    for (int t = 0; t < 128; t++) {
        floatx4 acc2[8][2];   // L2 accumulators, live across the P2a->P2b barrier

        // ============ P1: layer 1 (waves 10-14, one node each) + x staging (wave 15) ============
        if (w >= 10 && w < 15) {
            const int p0 = P0t[n1], p1 = P1t[n1];
            const int xb = (t & 1) * 160;
            half8 bfr[8];
            #pragma unroll
            for (int kk = 0; kk < 4; kk++)
                #pragma unroll
                for (int nt = 0; nt < 2; nt++) {
                    int p = (kk < 2) ? p0 : p1;
                    int row = nt*16 + cl;
                    int ff = (kk & 1)*32 + quad*8;
                    bfr[kk*2+nt] = *(const half8*)&S[cur*10240 + p*2048 + row*64 + SWZ(row,ff)];
                }
            #pragma unroll
            for (int h = 0; h < 2; h++) {
                floatx4 acc[8][2];
                #pragma unroll
                for (int mt = 0; mt < 8; mt++) {
                    int fb = (h*8+mt)*16 + quad*4;
                    floatx4 bv = *(const floatx4*)&cons[B1C + n1*256 + fb];
                    floatx4 u0 = *(const floatx4*)&cons[W1XC + (n1*2+0)*256 + fb];
                    floatx4 u1 = *(const floatx4*)&cons[W1XC + (n1*2+1)*256 + fb];
                    #pragma unroll
                    for (int nt = 0; nt < 2; nt++) {
                        float xa = xq[xb + p0*32 + nt*16 + cl];
                        float xc = xq[xb + p1*32 + nt*16 + cl];
                        #pragma unroll
                        for (int r = 0; r < 4; r++)
                            acc[mt][nt][r] = bv[r] + u0[r]*xa + u1[r]*xc;
                    }
                }
                #pragma unroll
                for (int kk = 0; kk < 4; kk++)
                    #pragma unroll
                    for (int nt = 0; nt < 2; nt++)
                        #pragma unroll
                        for (int mt = 0; mt < 8; mt++)
                            acc[mt][nt] = __builtin_amdgcn_mfma_f32_16x16x32_f16(
                                wf[(h*8+mt)*4+kk], bfr[kk*2+nt], acc[mt][nt], 0,0,0);
                #pragma unroll
                for (int mt = 0; mt < 8; mt++) {
                    int fb = (h*8+mt)*16 + quad*4;
                    #pragma unroll
                    for (int nt = 0; nt < 2; nt++) {
                        int row = nt*16 + cl;
                        union { _Float16 hh[4]; unsigned long long u; } pk;
                        #pragma unroll
                        for (int r = 0; r < 4; r++) {
                            float v = acc[mt][nt][r]; v = v > 0.f ? v : 0.f;
                            pk.hh[r] = (_Float16)v;
                        }
                        *(unsigned long long*)&H[n1*8192 + row*256 + SWZ(row,fb)] = pk.u;
                    }
                }
            }
        } else if (w == 15) {
            if (t < 127) {
                #pragma unroll
                for (int it = 0; it < 3; it++) {
                    int j = it*64 + lane;
                    if (j < 160) {
                        int p = j >> 5, r = j & 31;
                        xq[((t+1)&1)*160 + j] = x[(size_t)(b0 + r)*640 + p*128 + (t+1)];
                    }
                }
            }
        }
        __syncthreads();

        // ============ P2a: layer 2 compute (waves 0-9) ============
        if (isL2) {
            #pragma unroll
            for (int mt = 0; mt < 8; mt++) {
                int fb = (mh*8+mt)*16 + quad*4;
                floatx4 bv = *(const floatx4*)&cons[B2C + n2*256 + fb];
                #pragma unroll
                for (int nt = 0; nt < 2; nt++) acc2[mt][nt] = bv;
            }
            #pragma unroll
            for (int kk = 0; kk < 8; kk++)
                #pragma unroll
                for (int nt = 0; nt < 2; nt++) {
                    int row = nt*16 + cl;
                    int ff = kk*32 + quad*8;
                    half8 bfr = *(const half8*)&H[n2*8192 + row*256 + SWZ(row,ff)];
                    #pragma unroll
                    for (int mt = 0; mt < 8; mt++)
                        acc2[mt][nt] = __builtin_amdgcn_mfma_f32_16x16x32_f16(
                            wf[mt*8+kk], bfr, acc2[mt][nt], 0,0,0);
                }
        }
        __syncthreads();

        // ============ P2b: write H2 over H1 (waves 0-9) ============
        if (isL2) {
            #pragma unroll
            for (int mt = 0; mt < 8; mt++) {
                int fb = (mh*8+mt)*16 + quad*4;
                #pragma unroll
                for (int nt = 0; nt < 2; nt++) {
                    int row = nt*16 + cl;
                    union { _Float16 hh[4]; unsigned long long u; } pk;
                    #pragma unroll
                    for (int r = 0; r < 4; r++) {
                        float v = acc2[mt][nt][r]; v = v > 0.f ? v : 0.f;
                        pk.hh[r] = (_Float16)v;
                    }
                    *(unsigned long long*)&H[n2*8192 + row*256 + SWZ(row,fb)] = pk.u;
                }
            }
        }
        __syncthreads();

        // ============ P3: layer 3 -> tanh -> new state (waves 0-9) ============
        if (isL2) {
            floatx4 a3[2][2];
            #pragma unroll
            for (int m = 0; m < 2; m++) {
                int fb = (mh*2+m)*16 + quad*4;
                floatx4 bv = *(const floatx4*)&cons[B3C + n2*64 + fb];
                #pragma unroll
                for (int nt = 0; nt < 2; nt++) a3[m][nt] = bv;
            }
            #pragma unroll
            for (int kk = 0; kk < 8; kk++)
                #pragma unroll
                for (int nt = 0; nt < 2; nt++) {
                    int row = nt*16 + cl;
                    int ff = kk*32 + quad*8;
                    half8 bfr = *(const half8*)&H[n2*8192 + row*256 + SWZ(row,ff)];
                    #pragma unroll
                    for (int m = 0; m < 2; m++)
                        a3[m][nt] = __builtin_amdgcn_mfma_f32_16x16x32_f16(
                            w3f[m*8+kk], bfr, a3[m][nt], 0,0,0);
                }
            #pragma unroll
            for (int m = 0; m < 2; m++) {
                int fb = (mh*2+m)*16 + quad*4;
                #pragma unroll
                for (int nt = 0; nt < 2; nt++) {
                    int row = nt*16 + cl;
                    union { _Float16 hh[4]; unsigned long long u; } pk;
                    #pragma unroll
                    for (int r = 0; r < 4; r++)
                        pk.hh[r] = (_Float16)tanhf(a3[m][nt][r]);
                    *(unsigned long long*)&S[(cur^1)*10240 + n2*2048 + row*64 + SWZ(row,fb)] = pk.u;
                }
            }
        }
        __syncthreads();
        cur ^= 1;
    }

    // ============ head: hpre = relu([x_127, states] @ Wo1 + bo1) ============
    {
        half8 of[10];
        #pragma unroll
        for (int i = 0; i < 10; i++)
            of[i] = *(const half8*)(wo1p + (size_t)(w*10 + i)*512 + lane*8);
        int fb = w*16 + quad*4;
        floatx4 aH[2];
        floatx4 bv = *(const floatx4*)&cons[BO1C + fb];
        #pragma unroll
        for (int nt = 0; nt < 2; nt++) {
            int row = nt*16 + cl;
            aH[nt] = bv;
            #pragma unroll
            for (int p = 0; p < 5; p++) {
                floatx4 wv = *(const floatx4*)&cons[WO1XC + p*256 + fb];
                float xv = xq[160 + p*32 + row];   // buffer 1 holds x_127
                #pragma unroll
                for (int r = 0; r < 4; r++) aH[nt][r] += wv[r]*xv;
            }
        }
        #pragma unroll
        for (int kk = 0; kk < 10; kk++) {
            int nd = kk >> 1, ff = (kk & 1)*32 + quad*8;
            #pragma unroll
            for (int nt = 0; nt < 2; nt++) {
                int row = nt*16 + cl;
                half8 bfr = *(const half8*)&S[cur*10240 + nd*2048 + row*64 + SWZ(row,ff)];
                aH[nt] = __builtin_amdgcn_mfma_f32_16x16x32_f16(of[kk], bfr, aH[nt], 0,0,0);
            }
        }
        #pragma unroll
        for (int nt = 0; nt < 2; nt++) {
            int row = nt*16 + cl;
            floatx4 v = aH[nt];
            #pragma unroll
            for (int r = 0; r < 4; r++) v[r] = v[r] > 0.f ? v[r] : 0.f;
            *(floatx4*)&hpre[(size_t)(b0 + row)*256 + fb] = v;
        }
    }
}

// ---------------- BN stats: partial sums over batch ----------------
__global__ __launch_bounds__(256) void bnstats_kernel(const float* __restrict__ hpre,
                                                      float* __restrict__ sums)
{
    int col = threadIdx.x;
    int r0 = blockIdx.x * 128;
    float s = 0.f, s2 = 0.f;
    for (int r = 0; r < 128; r++) {
        float v = hpre[(size_t)(r0 + r)*256 + col];
        s += v; s2 += v*v;
    }
    atomicAdd(&sums[col], s);
    atomicAdd(&sums[256 + col], s2);
}

// ---------------- normalize + Wo2 + softmax: one wave per row ----------------
__global__ __launch_bounds__(256) void head_kernel(
    const float* __restrict__ hpre, const float* __restrict__ sums,
    const float* __restrict__ gamma, const float* __restrict__ beta,
    const float* __restrict__ Wo2, const float* __restrict__ bo2,
    float* __restrict__ out)
{
    int row  = blockIdx.x * 4 + (threadIdx.x >> 6);
    int lane = threadIdx.x & 63;
    floatx4 h  = *(const floatx4*)&hpre[(size_t)row*256 + lane*4];
    floatx4 sm = *(const floatx4*)&sums[lane*4];
    floatx4 sq = *(const floatx4*)&sums[256 + lane*4];
    floatx4 g  = *(const floatx4*)&gamma[lane*4];
    floatx4 bb = *(const floatx4*)&beta[lane*4];
    float acc[7] = {0.f,0.f,0.f,0.f,0.f,0.f,0.f};
    #pragma unroll
    for (int e = 0; e < 4; e++) {
        float mu  = sm[e] * (1.f/8192.f);
        float var = sq[e] * (1.f/8192.f) - mu*mu;
        float hn  = (h[e] - mu) * rsqrtf(var + 1e-5f) * g[e] + bb[e];
        int colg = lane*4 + e;
        #pragma unroll
        for (int j = 0; j < 7; j++) acc[j] += hn * Wo2[colg*7 + j];
    }
    #pragma unroll
    for (int off = 1; off < 64; off <<= 1) {
        #pragma unroll
        for (int j = 0; j < 7; j++) acc[j] += __shfl_xor(acc[j], off, 64);
    }
    float z[7], m = -1e30f;
    #pragma unroll
    for (int j = 0; j < 7; j++) { z[j] = acc[j] + bo2[j]; m = fmaxf(m, z[j]); }
    float se = 0.f;
    #pragma unroll
    for (int j = 0; j < 7; j++) { z[j] = expf(z[j] - m); se += z[j]; }
    if (lane < 7) out[(size_t)row*7 + lane] = z[lane] / se;
}

extern "C" void kernel_launch(void* const* d_in, const int* in_sizes, int n_in,
                              void* d_out, int out_size, void* d_ws, size_t ws_size,
                              hipStream_t stream)
{
    const float* x    = (const float*)d_in[0];
    const float* W1   = (const float*)d_in[1];
    const float* b1   = (const float*)d_in[2];
    const float* W2   = (const float*)d_in[3];
    const float* b2   = (const float*)d_in[4];
    const float* W3   = (const float*)d_in[5];
    const float* b3   = (const float*)d_in[6];
    const float* Wo1  = (const float*)d_in[7];
    const float* bo1  = (const float*)d_in[8];
    const float* gamma= (const float*)d_in[9];
    const float* beta = (const float*)d_in[10];
    const float* Wo2  = (const float*)d_in[11];
    const float* bo2  = (const float*)d_in[12];
    float* out = (float*)d_out;

    if (ws_size < WS_NEEDED) return;
    char* ws = (char*)d_ws;
    float*     hpre = (float*)(ws + HPRE_OFF);
    float*     sums = (float*)(ws + SUM_OFF);
    _Float16*  w1p  = (_Float16*)(ws + PACK_OFF);
    _Float16*  w2p  = w1p + W1P_HALFS;
    _Float16*  w3p  = w2p + W2P_HALFS;
    _Float16*  wo1p = w3p + W3P_HALFS;

    static int lds_set = 0;
    if (!lds_set) {
        hipFuncSetAttribute((const void*)scan_kernel,
                            hipFuncAttributeMaxDynamicSharedMemorySize, SMEM_BYTES);
        lds_set = 1;
    }

    pack_kernel<<<320, 256, 0, stream>>>(W1, W2, W3, Wo1, w1p, w2p, w3p, wo1p, sums);
    scan_kernel<<<256, 1024, SMEM_BYTES, stream>>>(x, W1, b1, b2, b3, Wo1, bo1,
                                                   w1p, w2p, w3p, wo1p, hpre);
    bnstats_kernel<<<64, 256, 0, stream>>>(hpre, sums);
    head_kernel<<<2048, 256, 0, stream>>>(hpre, sums, gamma, beta, Wo2, bo2, out);
}

// Round 3
// 7126.728 us; speedup vs baseline: 1.6846x; 1.6846x over previous
//
#include <hip/hip_runtime.h>
#include <cstddef>
#include <cstdint>

typedef _Float16 half8  __attribute__((ext_vector_type(8)));
typedef _Float16 half4v __attribute__((ext_vector_type(4)));
typedef float    floatx4 __attribute__((ext_vector_type(4)));

#define NB 51                       // blocks per node, grid = 5*NB = 255
#define SW(row) (((row)&7)*8)       // LDS xor-swizzle (8-half granules)

// ---- ws layout (bytes) ----
#define HPRE_OFF 0u                 // 8192*256 f32
#define SUM_OFF  8388608u           // 512 f32
#define FLAG_OFF 8390656u           // 256 int
#define CONS_OFF 8391680u           // 256 int
#define SG_OFF   8392704u           // 2*5*8192*64 f16 = 10485760
#define PACK_OFF 18878464u
#define W1P_HALFS 163840
#define W2P_HALFS 327680
#define W3P_HALFS 81920
#define WS_NEEDED 20189184u

// ---- dynamic smem layout for scan (bytes) ----
// Sp  [2][176][64] f16 = 45056
// H1  [64][256] f16    = 32768   (chunk buffer)
// H2  [64][256] f16    = 32768
// xls [2][176] f32     = 1408
// cns [1088] f32       = 4352    (b1n 0..255, b2n 256..511, b3n 512..575, w1x 576..1087)
#define SMEM_BYTES 116352

// ---------------- pack: f32 weights -> f16 MFMA A-fragment order ----------------
// A-frag 16x16x32: lane holds A[m = mt*16 + (lane&15)][k = kk*32 + (lane>>4)*8 + j]
__global__ __launch_bounds__(256) void pack_kernel(
    const float* __restrict__ W1, const float* __restrict__ W2,
    const float* __restrict__ W3, const float* __restrict__ Wo1,
    _Float16* __restrict__ w1p, _Float16* __restrict__ w2p,
    _Float16* __restrict__ w3p, _Float16* __restrict__ wo1p,
    float* __restrict__ sums, int* __restrict__ flags, int* __restrict__ cons)
{
    int id = blockIdx.x * 256 + threadIdx.x;
    if (id < 512) sums[id] = 0.f;
    if (id < 256) { flags[id] = 0; cons[id] = 0; }
    int f = id >> 6;
    int lane = id & 63;
    int q = lane >> 4, cl = lane & 15;
    if (f < 320) {                           // W1 state rows: frag (n*16+mt)*4+kk
        int kk = f & 3, mt = (f >> 2) & 15, n = f >> 6;
        #pragma unroll
        for (int j = 0; j < 8; j++)
            w1p[(size_t)f*512 + lane*8 + j] =
                (_Float16)W1[(size_t)(n*130 + 2 + kk*32 + q*8 + j)*256 + mt*16 + cl];
    } else if (f < 960) {                    // W2: frag (n*16+mt)*8+kk
        int g = f - 320;
        int kk = g & 7, mt = (g >> 3) & 15, n = g >> 7;
        #pragma unroll
        for (int j = 0; j < 8; j++)
            w2p[(size_t)g*512 + lane*8 + j] =
                (_Float16)W2[(size_t)(n*256 + kk*32 + q*8 + j)*256 + mt*16 + cl];
    } else if (f < 1120) {                   // W3: frag (n*4+mt)*8+kk
        int g = f - 960;
        int kk = g & 7, mt = (g >> 3) & 3, n = g >> 5;
        #pragma unroll
        for (int j = 0; j < 8; j++)
            w3p[(size_t)g*512 + lane*8 + j] =
                (_Float16)W3[(size_t)(n*256 + kk*32 + q*8 + j)*64 + mt*16 + cl];
    } else if (f < 1280) {                   // Wo1 state rows: frag mt*10+kk
        int g = f - 1120;
        int kk = g % 10, mt = g / 10;
        #pragma unroll
        for (int j = 0; j < 8; j++)
            wo1p[(size_t)g*512 + lane*8 + j] =
                (_Float16)Wo1[(size_t)(5 + kk*32 + q*8 + j)*256 + mt*16 + cl];
    }
}

// ---------------- scan: node-specialized persistent blocks ----------------
template<int NT>
__device__ __attribute__((always_inline)) void scan_impl(
    const float* __restrict__ x, const float* __restrict__ W1,
    const float* __restrict__ b1, const float* __restrict__ b2, const float* __restrict__ b3,
    const _Float16* __restrict__ w1p, const _Float16* __restrict__ w2p,
    const _Float16* __restrict__ w3p,
    _Float16* __restrict__ Sg, int* flags, int* cons,
    char* smem, int n, int idx, int r0)
{
    constexpr int BB  = NT * 16;
    constexpr int NCH = 3;
    _Float16* Sp  = (_Float16*)smem;                 // [2][176][64] swizzled
    _Float16* H1  = (_Float16*)(smem + 45056);       // [64][256] swizzled (chunk)
    _Float16* H2  = (_Float16*)(smem + 77824);
    float*    xls = (float*)(smem + 110592);         // [2][176]
    float*    cns = (float*)(smem + 112000);         // 1088 floats

    const int tid = threadIdx.x, w = tid >> 6, lane = tid & 63;
    const int quad = lane >> 4, cl = lane & 15;
    const int P0t[5] = {3,0,0,1,2}, P1t[5] = {4,4,1,2,3};
    const int p0 = P0t[n], p1 = P1t[n];
    const int myix = n*NB + idx, f0ix = p0*NB + idx, f1ix = p1*NB + idx;
    const int mt3 = w & 3, half = w >> 2;

    // ---- resident weight fragments (loaded once) ----
    half8 w1f[2][4], w2f[2][8], w3f[8];
    #pragma unroll
    for (int i = 0; i < 2; i++) {
        int mt = 2*w + i;
        #pragma unroll
        for (int kk = 0; kk < 4; kk++)
            w1f[i][kk] = *(const half8*)(w1p + (size_t)((n*16 + mt)*4 + kk)*512 + lane*8);
        #pragma unroll
        for (int kk = 0; kk < 8; kk++)
            w2f[i][kk] = *(const half8*)(w2p + (size_t)((n*16 + mt)*8 + kk)*512 + lane*8);
    }
    #pragma unroll
    for (int kk = 0; kk < 8; kk++)
        w3f[kk] = *(const half8*)(w3p + (size_t)((n*4 + mt3)*8 + kk)*512 + lane*8);

    // ---- stage per-node constants ----
    for (int i = tid; i < 1088; i += 512) {
        float v;
        if      (i < 256) v = b1[n*256 + i];
        else if (i < 512) v = b2[n*256 + i - 256];
        else if (i < 576) v = b3[n*64  + i - 512];
        else { int j = i - 576; v = W1[(size_t)(n*130 + (j>>8))*256 + (j & 255)]; }
        cns[i] = v;
    }

    auto stage_rows = [&](int first_row, int R, int buf) {
        int tot = 2*R*8;
        for (int i = tid; i < tot; i += 512) {
            int pp = i >= R*8;
            int rem = i - pp*R*8;
            int rl = rem >> 3, g8 = rem & 7;
            int grow = first_row + rl;
            const _Float16* src = Sg + ((size_t)((buf*5 + (pp ? p1 : p0))*8192 + r0 + grow))*64 + g8*8;
            *(half8*)&Sp[pp*11264 + grow*64 + ((g8*8) ^ SW(grow))] = *(const half8*)src;
        }
    };

    for (int t = 0; t < 128; t++) {
        // ---- phase 0: neighbor sync ----
        if (t > 0 && tid < 2) {
            int* fp = &flags[tid ? f1ix : f0ix];
            while (__hip_atomic_load(fp, __ATOMIC_RELAXED, __HIP_MEMORY_SCOPE_AGENT) < t)
                __builtin_amdgcn_s_sleep(4);
        }
        if (t >= 2 && tid == 2) {
            int need = 2*(t-1);
            while (__hip_atomic_load(&cons[myix], __ATOMIC_RELAXED, __HIP_MEMORY_SCOPE_AGENT) < need)
                __builtin_amdgcn_s_sleep(4);
        }
        __syncthreads();
        if (t > 0) __threadfence();   // acquire: invalidate stale L1/L2

        // ---- phase 1: stage chunk-0 parent rows + x_t ----
        if (t > 0) stage_rows(0, 64, (t-1) & 1);
        for (int i = tid; i < 2*BB; i += 512) {
            int pp = i >= BB; int rl = i - pp*BB;
            xls[pp*176 + rl] = x[(size_t)(r0 + rl)*640 + (pp ? p1 : p0)*128 + t];
        }
        __syncthreads();

        // ---- phase 2: chunks of 4 row-tiles: L1 -> L2 -> L3 ----
        #pragma unroll
        for (int c = 0; c < NCH; c++) {
            const int rem_nt = NT - c*4;
            const int cnt = rem_nt < 4 ? rem_nt : 4;
            const int base16 = c*64;

            // stage next chunk's parent rows (overlapped with L1 compute)
            if (t > 0 && c + 1 < NCH) {
                int fr = (c+1)*64;
                int R = BB - fr; if (R > 64) R = 64;
                stage_rows(fr, R, (t-1) & 1);
            }

            // ---- L1: out 256 feats, K = parents' states (+ rank-2 x terms) ----
            floatx4 a1[2][4];
            #pragma unroll
            for (int i = 0; i < 2; i++) {
                int fb = (2*w + i)*16 + quad*4;
                floatx4 bv = *(const floatx4*)&cns[fb];
                floatx4 u0 = *(const floatx4*)&cns[576 + fb];
                floatx4 u1 = *(const floatx4*)&cns[832 + fb];
                #pragma unroll
                for (int j = 0; j < 4; j++) if (j < cnt) {
                    int rb = base16 + j*16 + cl;
                    float xa = xls[rb], xc = xls[176 + rb];
                    a1[i][j] = bv + u0*xa + u1*xc;
                }
            }
            if (t > 0) {
                #pragma unroll
                for (int kk = 0; kk < 4; kk++)
                    #pragma unroll
                    for (int j = 0; j < 4; j++) if (j < cnt) {
                        half8 bf = *(const half8*)&Sp[(kk>>1)*11264 + (base16 + j*16 + cl)*64
                                                      + (((kk&1)*32 + quad*8) ^ SW(cl))];
                        a1[0][j] = __builtin_amdgcn_mfma_f32_16x16x32_f16(w1f[0][kk], bf, a1[0][j], 0,0,0);
                        a1[1][j] = __builtin_amdgcn_mfma_f32_16x16x32_f16(w1f[1][kk], bf, a1[1][j], 0,0,0);
                    }
            }
            #pragma unroll
            for (int i = 0; i < 2; i++) {
                int fb = (2*w + i)*16 + quad*4;
                #pragma unroll
                for (int j = 0; j < 4; j++) if (j < cnt) {
                    int rl = j*16 + cl;
                    half4v pk;
                    #pragma unroll
                    for (int r = 0; r < 4; r++) {
                        float v = a1[i][j][r]; v = v > 0.f ? v : 0.f;
                        pk[r] = (_Float16)v;
                    }
                    *(half4v*)&H1[rl*256 + (fb ^ SW(cl))] = pk;
                }
            }
            __syncthreads();   // L1 done (also next-chunk staging drained)

            if (c == NCH-1 && t > 0 && tid < 2)
                __hip_atomic_fetch_add(&cons[tid ? f1ix : f0ix], 1,
                                       __ATOMIC_RELAXED, __HIP_MEMORY_SCOPE_AGENT);

            // ---- L2: 256 -> 256 ----
            floatx4 a2[2][4];
            #pragma unroll
            for (int i = 0; i < 2; i++) {
                int fb = (2*w + i)*16 + quad*4;
                floatx4 bv = *(const floatx4*)&cns[256 + fb];
                #pragma unroll
                for (int j = 0; j < 4; j++) if (j < cnt) a2[i][j] = bv;
            }
            #pragma unroll
            for (int kk = 0; kk < 8; kk++)
                #pragma unroll
                for (int j = 0; j < 4; j++) if (j < cnt) {
                    half8 bf = *(const half8*)&H1[(j*16 + cl)*256 + ((kk*32 + quad*8) ^ SW(cl))];
                    a2[0][j] = __builtin_amdgcn_mfma_f32_16x16x32_f16(w2f[0][kk], bf, a2[0][j], 0,0,0);
                    a2[1][j] = __builtin_amdgcn_mfma_f32_16x16x32_f16(w2f[1][kk], bf, a2[1][j], 0,0,0);
                }
            #pragma unroll
            for (int i = 0; i < 2; i++) {
                int fb = (2*w + i)*16 + quad*4;
                #pragma unroll
                for (int j = 0; j < 4; j++) if (j < cnt) {
                    int rl = j*16 + cl;
                    half4v pk;
                    #pragma unroll
                    for (int r = 0; r < 4; r++) {
                        float v = a2[i][j][r]; v = v > 0.f ? v : 0.f;
                        pk[r] = (_Float16)v;
                    }
                    *(half4v*)&H2[rl*256 + (fb ^ SW(cl))] = pk;
                }
            }
            __syncthreads();   // L2 done

            // ---- L3: 256 -> 64, tanh, write state to global ----
            {
                int f3 = mt3*16 + quad*4;
                floatx4 bv = *(const floatx4*)&cns[512 + f3];
                floatx4 a3[2];
                #pragma unroll
                for (int jj = 0; jj < 2; jj++) a3[jj] = bv;
                #pragma unroll
                for (int kk = 0; kk < 8; kk++)
                    #pragma unroll
                    for (int jj = 0; jj < 2; jj++) {
                        int j = half*2 + jj;
                        if (j < cnt) {
                            half8 bf = *(const half8*)&H2[(j*16 + cl)*256 + ((kk*32 + quad*8) ^ SW(cl))];
                            a3[jj] = __builtin_amdgcn_mfma_f32_16x16x32_f16(w3f[kk], bf, a3[jj], 0,0,0);
                        }
                    }
                #pragma unroll
                for (int jj = 0; jj < 2; jj++) {
                    int j = half*2 + jj;
                    if (j < cnt) {
                        int grow = r0 + base16 + j*16 + cl;
                        half4v pk;
                        #pragma unroll
                        for (int r = 0; r < 4; r++) pk[r] = (_Float16)tanhf(a3[jj][r]);
                        *(half4v*)&Sg[((size_t)(((t&1)*5 + n)*8192 + grow))*64 + f3] = pk;
                    }
                }
            }
            // no barrier: next chunk's L1 writes H1 (disjoint from H2 readers)
        }

        // ---- publish ----
        __syncthreads();   // drains state stores (vmcnt) for all waves
        if (tid == 0) {
            __threadfence();   // release: writeback L2
            __hip_atomic_store(&flags[myix], t+1, __ATOMIC_RELAXED, __HIP_MEMORY_SCOPE_AGENT);
        }
    }
}

__global__ __launch_bounds__(512, 2) void scan_kernel(
    const float* __restrict__ x, const float* __restrict__ W1,
    const float* __restrict__ b1, const float* __restrict__ b2, const float* __restrict__ b3,
    const _Float16* __restrict__ w1p, const _Float16* __restrict__ w2p,
    const _Float16* __restrict__ w3p,
    _Float16* __restrict__ Sg, int* flags, int* cons)
{
    extern __shared__ char smem[];
    int b = blockIdx.x;
    int n = b / NB, idx = b % NB;
    int r0 = idx < 2 ? idx*176 : 352 + (idx-2)*160;
    if (idx < 2)
        scan_impl<11>(x, W1, b1, b2, b3, w1p, w2p, w3p, Sg, flags, cons, smem, n, idx, r0);
    else
        scan_impl<10>(x, W1, b1, b2, b3, w1p, w2p, w3p, Sg, flags, cons, smem, n, idx, r0);
}

// ---------------- hpre: relu([x_127, states] @ Wo1 + bo1) ----------------
__global__ __launch_bounds__(512) void hpre_kernel(
    const float* __restrict__ x, const float* __restrict__ Wo1, const float* __restrict__ bo1,
    const _Float16* __restrict__ wo1p, const _Float16* __restrict__ Sg,
    float* __restrict__ hpre)
{
    __shared__ float x5[640];     // [5][128]
    __shared__ float wxo[1280];   // Wo1 rows 0..4
    __shared__ float bo1c[256];
    int tid = threadIdx.x, w = tid >> 6, lane = tid & 63;
    int quad = lane >> 4, cl = lane & 15;
    int r0h = blockIdx.x * 128;

    for (int i = tid; i < 640; i += 512)
        x5[i] = x[(size_t)(r0h + (i & 127))*640 + (i >> 7)*128 + 127];
    for (int i = tid; i < 1280; i += 512) wxo[i] = Wo1[i];
    if (tid < 256) bo1c[tid] = bo1[tid];

    half8 of[2][10];
    #pragma unroll
    for (int i = 0; i < 2; i++) {
        int mt = 2*w + i;
        #pragma unroll
        for (int kk = 0; kk < 10; kk++)
            of[i][kk] = *(const half8*)(wo1p + (size_t)(mt*10 + kk)*512 + lane*8);
    }
    __syncthreads();

    floatx4 acc[2][8];
    #pragma unroll
    for (int i = 0; i < 2; i++) {
        int fb = (2*w + i)*16 + quad*4;
        floatx4 bv = *(const floatx4*)&bo1c[fb];
        #pragma unroll
        for (int nt = 0; nt < 8; nt++) {
            floatx4 a = bv;
            #pragma unroll
            for (int p = 0; p < 5; p++) {
                floatx4 wv = *(const floatx4*)&wxo[p*256 + fb];
                float xv = x5[p*128 + nt*16 + cl];
                a += wv * xv;
            }
            acc[i][nt] = a;
        }
    }
    #pragma unroll
    for (int kk = 0; kk < 10; kk++) {
        int nd = kk >> 1;
        #pragma unroll
        for (int nt = 0; nt < 8; nt++) {
            const _Float16* sp = Sg + ((size_t)((5 + nd)*8192 + r0h + nt*16 + cl))*64
                                    + (kk & 1)*32 + quad*8;   // buf 1 = state(127)
            half8 bf = *(const half8*)sp;
            acc[0][nt] = __builtin_amdgcn_mfma_f32_16x16x32_f16(of[0][kk], bf, acc[0][nt], 0,0,0);
            acc[1][nt] = __builtin_amdgcn_mfma_f32_16x16x32_f16(of[1][kk], bf, acc[1][nt], 0,0,0);
        }
    }
    #pragma unroll
    for (int i = 0; i < 2; i++) {
        int fb = (2*w + i)*16 + quad*4;
        #pragma unroll
        for (int nt = 0; nt < 8; nt++) {
            floatx4 v = acc[i][nt];
            #pragma unroll
            for (int r = 0; r < 4; r++) v[r] = v[r] > 0.f ? v[r] : 0.f;
            *(floatx4*)&hpre[(size_t)(r0h + nt*16 + cl)*256 + fb] = v;
        }
    }
}

// ---------------- BN stats ----------------
__global__ __launch_bounds__(256) void bnstats_kernel(const float* __restrict__ hpre,
                                                      float* __restrict__ sums)
{
    int col = threadIdx.x;
    int r0 = blockIdx.x * 128;
    float s = 0.f, s2 = 0.f;
    for (int r = 0; r < 128; r++) {
        float v = hpre[(size_t)(r0 + r)*256 + col];
        s += v; s2 += v*v;
    }
    atomicAdd(&sums[col], s);
    atomicAdd(&sums[256 + col], s2);
}

// ---------------- normalize + Wo2 + softmax ----------------
__global__ __launch_bounds__(256) void head_kernel(
    const float* __restrict__ hpre, const float* __restrict__ sums,
    const float* __restrict__ gamma, const float* __restrict__ beta,
    const float* __restrict__ Wo2, const float* __restrict__ bo2,
    float* __restrict__ out)
{
    int row  = blockIdx.x * 4 + (threadIdx.x >> 6);
    int lane = threadIdx.x & 63;
    floatx4 h  = *(const floatx4*)&hpre[(size_t)row*256 + lane*4];
    floatx4 sm = *(const floatx4*)&sums[lane*4];
    floatx4 sq = *(const floatx4*)&sums[256 + lane*4];
    floatx4 g  = *(const floatx4*)&gamma[lane*4];
    floatx4 bb = *(const floatx4*)&beta[lane*4];
    float acc[7] = {0.f,0.f,0.f,0.f,0.f,0.f,0.f};
    #pragma unroll
    for (int e = 0; e < 4; e++) {
        float mu  = sm[e] * (1.f/8192.f);
        float var = sq[e] * (1.f/8192.f) - mu*mu;
        float hn  = (h[e] - mu) * rsqrtf(var + 1e-5f) * g[e] + bb[e];
        int colg = lane*4 + e;
        #pragma unroll
        for (int j = 0; j < 7; j++) acc[j] += hn * Wo2[colg*7 + j];
    }
    #pragma unroll
    for (int off = 1; off < 64; off <<= 1) {
        #pragma unroll
        for (int j = 0; j < 7; j++) acc[j] += __shfl_xor(acc[j], off, 64);
    }
    float z[7], m = -1e30f;
    #pragma unroll
    for (int j = 0; j < 7; j++) { z[j] = acc[j] + bo2[j]; m = fmaxf(m, z[j]); }
    float se = 0.f;
    #pragma unroll
    for (int j = 0; j < 7; j++) { z[j] = expf(z[j] - m); se += z[j]; }
    if (lane < 7) out[(size_t)row*7 + lane] = z[lane] / se;
}

extern "C" void kernel_launch(void* const* d_in, const int* in_sizes, int n_in,
                              void* d_out, int out_size, void* d_ws, size_t ws_size,
                              hipStream_t stream)
{
    const float* x    = (const float*)d_in[0];
    const float* W1   = (const float*)d_in[1];
    const float* b1   = (const float*)d_in[2];
    const float* W2   = (const float*)d_in[3];
    const float* b2   = (const float*)d_in[4];
    const float* W3   = (const float*)d_in[5];
    const float* b3   = (const float*)d_in[6];
    const float* Wo1  = (const float*)d_in[7];
    const float* bo1  = (const float*)d_in[8];
    const float* gamma= (const float*)d_in[9];
    const float* beta = (const float*)d_in[10];
    const float* Wo2  = (const float*)d_in[11];
    const float* bo2  = (const float*)d_in[12];
    float* out = (float*)d_out;

    if (ws_size < WS_NEEDED) return;
    char* ws = (char*)d_ws;
    float*     hpre  = (float*)(ws + HPRE_OFF);
    float*     sums  = (float*)(ws + SUM_OFF);
    int*       flags = (int*)(ws + FLAG_OFF);
    int*       cons  = (int*)(ws + CONS_OFF);
    _Float16*  Sg    = (_Float16*)(ws + SG_OFF);
    _Float16*  w1p   = (_Float16*)(ws + PACK_OFF);
    _Float16*  w2p   = w1p + W1P_HALFS;
    _Float16*  w3p   = w2p + W2P_HALFS;
    _Float16*  wo1p  = w3p + W3P_HALFS;

    hipFuncSetAttribute((const void*)scan_kernel,
                        hipFuncAttributeMaxDynamicSharedMemorySize, SMEM_BYTES);

    pack_kernel<<<320, 256, 0, stream>>>(W1, W2, W3, Wo1, w1p, w2p, w3p, wo1p,
                                         sums, flags, cons);
    scan_kernel<<<5*NB, 512, SMEM_BYTES, stream>>>(x, W1, b1, b2, b3,
                                                   w1p, w2p, w3p, Sg, flags, cons);
    hpre_kernel<<<64, 512, 0, stream>>>(x, Wo1, bo1, wo1p, Sg, hpre);
    bnstats_kernel<<<64, 256, 0, stream>>>(hpre, sums);
    head_kernel<<<2048, 256, 0, stream>>>(hpre, sums, gamma, beta, Wo2, bo2, out);
}

// Round 4
// 2052.841 us; speedup vs baseline: 5.8484x; 3.4716x over previous
//
#include <hip/hip_runtime.h>
#include <cstddef>
#include <cstdint>

typedef _Float16 half8  __attribute__((ext_vector_type(8)));
typedef _Float16 half4v __attribute__((ext_vector_type(4)));
typedef float    floatx4 __attribute__((ext_vector_type(4)));
typedef unsigned long long u64;

#define NB 51                       // blocks per node, grid = 5*NB = 255
#define SW(row) (((row)&7)*8)       // LDS xor-swizzle (8-half granules)

#define AGENT_LD(p)    __hip_atomic_load((p), __ATOMIC_RELAXED, __HIP_MEMORY_SCOPE_AGENT)
#define AGENT_ST(p,v)  __hip_atomic_store((p), (v), __ATOMIC_RELAXED, __HIP_MEMORY_SCOPE_AGENT)

// ---- ws layout (bytes) ----
#define HPRE_OFF 0u                 // 8192*256 f32
#define SUM_OFF  8388608u           // 512 f32
#define FLAG_OFF 8390656u           // 256 int
#define CONS_OFF 8391680u           // 256 int
#define SG_OFF   8392704u           // 2*5*8192*64 f16 = 10485760
#define PACK_OFF 18878464u
#define W1P_HALFS 163840
#define W2P_HALFS 327680
#define W3P_HALFS 81920
#define WS_NEEDED 20189184u

// ---- dynamic smem layout for scan (bytes) ----
// Sp  [2][176][64] f16 = 45056
// H1  [64][256] f16    = 32768   (chunk buffer)
// H2  [64][256] f16    = 32768
// xls [2][176] f32     = 1408
// cns [1088] f32       = 4352
#define SMEM_BYTES 116352

// ---------------- pack: f32 weights -> f16 MFMA A-fragment order ----------------
// A-frag 16x16x32: lane holds A[m = mt*16 + (lane&15)][k = kk*32 + (lane>>4)*8 + j]
__global__ __launch_bounds__(256) void pack_kernel(
    const float* __restrict__ W1, const float* __restrict__ W2,
    const float* __restrict__ W3, const float* __restrict__ Wo1,
    _Float16* __restrict__ w1p, _Float16* __restrict__ w2p,
    _Float16* __restrict__ w3p, _Float16* __restrict__ wo1p,
    float* __restrict__ sums, int* __restrict__ flags, int* __restrict__ cons)
{
    int id = blockIdx.x * 256 + threadIdx.x;
    if (id < 512) sums[id] = 0.f;
    if (id < 256) { flags[id] = 0; cons[id] = 0; }
    int f = id >> 6;
    int lane = id & 63;
    int q = lane >> 4, cl = lane & 15;
    if (f < 320) {                           // W1 state rows: frag (n*16+mt)*4+kk
        int kk = f & 3, mt = (f >> 2) & 15, n = f >> 6;
        #pragma unroll
        for (int j = 0; j < 8; j++)
            w1p[(size_t)f*512 + lane*8 + j] =
                (_Float16)W1[(size_t)(n*130 + 2 + kk*32 + q*8 + j)*256 + mt*16 + cl];
    } else if (f < 960) {                    // W2: frag (n*16+mt)*8+kk
        int g = f - 320;
        int kk = g & 7, mt = (g >> 3) & 15, n = g >> 7;
        #pragma unroll
        for (int j = 0; j < 8; j++)
            w2p[(size_t)g*512 + lane*8 + j] =
                (_Float16)W2[(size_t)(n*256 + kk*32 + q*8 + j)*256 + mt*16 + cl];
    } else if (f < 1120) {                   // W3: frag (n*4+mt)*8+kk
        int g = f - 960;
        int kk = g & 7, mt = (g >> 3) & 3, n = g >> 5;
        #pragma unroll
        for (int j = 0; j < 8; j++)
            w3p[(size_t)g*512 + lane*8 + j] =
                (_Float16)W3[(size_t)(n*256 + kk*32 + q*8 + j)*64 + mt*16 + cl];
    } else if (f < 1280) {                   // Wo1 state rows: frag mt*10+kk
        int g = f - 1120;
        int kk = g % 10, mt = g / 10;
        #pragma unroll
        for (int j = 0; j < 8; j++)
            wo1p[(size_t)g*512 + lane*8 + j] =
                (_Float16)Wo1[(size_t)(5 + kk*32 + q*8 + j)*256 + mt*16 + cl];
    }
}

// ---------------- scan: node-specialized persistent blocks ----------------
// Cross-block coherence: ALL Sg/flag/cons traffic uses agent-scope (sc1)
// atomics -> served at the shared LLC, no L1/L2 staleness, NO fences needed.
// __syncthreads drains vmcnt(0) per wave, so state stores are LLC-visible
// before the flag store that follows the barrier.
template<int NT>
__device__ __attribute__((always_inline)) void scan_impl(
    const float* __restrict__ x, const float* __restrict__ W1,
    const float* __restrict__ b1, const float* __restrict__ b2, const float* __restrict__ b3,
    const _Float16* __restrict__ w1p, const _Float16* __restrict__ w2p,
    const _Float16* __restrict__ w3p,
    _Float16* __restrict__ Sg, int* flags, int* cons,
    char* smem, int n, int idx, int r0)
{
    constexpr int BB  = NT * 16;
    constexpr int NCH = 3;
    _Float16* Sp  = (_Float16*)smem;                 // [2][176][64] swizzled
    _Float16* H1  = (_Float16*)(smem + 45056);       // [64][256] swizzled (chunk)
    _Float16* H2  = (_Float16*)(smem + 77824);
    float*    xls = (float*)(smem + 110592);         // [2][176]
    float*    cns = (float*)(smem + 112000);         // 1088 floats

    const int tid = threadIdx.x, w = tid >> 6, lane = tid & 63;
    const int quad = lane >> 4, cl = lane & 15;
    const int P0t[5] = {3,0,0,1,2}, P1t[5] = {4,4,1,2,3};
    const int p0 = P0t[n], p1 = P1t[n];
    const int myix = n*NB + idx, f0ix = p0*NB + idx, f1ix = p1*NB + idx;
    const int mt3 = w & 3, half = w >> 2;

    // ---- resident weight fragments (loaded once) ----
    half8 w1f[2][4], w2f[2][8], w3f[8];
    #pragma unroll
    for (int i = 0; i < 2; i++) {
        int mt = 2*w + i;
        #pragma unroll
        for (int kk = 0; kk < 4; kk++)
            w1f[i][kk] = *(const half8*)(w1p + (size_t)((n*16 + mt)*4 + kk)*512 + lane*8);
        #pragma unroll
        for (int kk = 0; kk < 8; kk++)
            w2f[i][kk] = *(const half8*)(w2p + (size_t)((n*16 + mt)*8 + kk)*512 + lane*8);
    }
    #pragma unroll
    for (int kk = 0; kk < 8; kk++)
        w3f[kk] = *(const half8*)(w3p + (size_t)((n*4 + mt3)*8 + kk)*512 + lane*8);

    // ---- stage per-node constants ----
    for (int i = tid; i < 1088; i += 512) {
        float v;
        if      (i < 256) v = b1[n*256 + i];
        else if (i < 512) v = b2[n*256 + i - 256];
        else if (i < 576) v = b3[n*64  + i - 512];
        else { int j = i - 576; v = W1[(size_t)(n*130 + (j>>8))*256 + (j & 255)]; }
        cns[i] = v;
    }

    auto stage_rows = [&](int first_row, int R, int buf) {
        int tot = 2*R*8;
        for (int i = tid; i < tot; i += 512) {
            int pp = i >= R*8;
            int rem = i - pp*R*8;
            int rl = rem >> 3, g8 = rem & 7;
            int grow = first_row + rl;
            u64* src = (u64*)(Sg + ((size_t)((buf*5 + (pp ? p1 : p0))*8192 + r0 + grow))*64 + g8*8);
            u64 lo = AGENT_LD(src);
            u64 hi = AGENT_LD(src + 1);
            union { u64 q[2]; half8 h; } u; u.q[0] = lo; u.q[1] = hi;
            *(half8*)&Sp[pp*11264 + grow*64 + ((g8*8) ^ SW(grow))] = u.h;
        }
    };

    for (int t = 0; t < 128; t++) {
        // ---- phase 0: neighbor sync (wave 0 only; no fences) ----
        if (t > 0 && tid < 2) {
            int* fp = &flags[tid ? f1ix : f0ix];
            while (AGENT_LD(fp) < t) __builtin_amdgcn_s_sleep(2);
        }
        if (t >= 2 && tid == 2) {
            int need = 2*(t-1);
            while (AGENT_LD(&cons[myix]) < need) __builtin_amdgcn_s_sleep(2);
        }
        __syncthreads();

        // ---- phase 1: stage chunk-0 parent rows + x_t ----
        if (t > 0) stage_rows(0, 64, (t-1) & 1);
        for (int i = tid; i < 2*BB; i += 512) {
            int pp = i >= BB; int rl = i - pp*BB;
            xls[pp*176 + rl] = x[(size_t)(r0 + rl)*640 + (pp ? p1 : p0)*128 + t];
        }
        __syncthreads();

        // ---- phase 2: chunks of 4 row-tiles: L1 -> L2 -> L3 ----
        #pragma unroll
        for (int c = 0; c < NCH; c++) {
            const int rem_nt = NT - c*4;
            const int cnt = rem_nt < 4 ? rem_nt : 4;
            const int base16 = c*64;

            // stage next chunk's parent rows (overlapped with L1 compute)
            if (t > 0 && c + 1 < NCH) {
                int fr = (c+1)*64;
                int R = BB - fr; if (R > 64) R = 64;
                stage_rows(fr, R, (t-1) & 1);
            }

            // ---- L1: out 256 feats, K = parents' states (+ rank-2 x terms) ----
            floatx4 a1[2][4];
            #pragma unroll
            for (int i = 0; i < 2; i++) {
                int fb = (2*w + i)*16 + quad*4;
                floatx4 bv = *(const floatx4*)&cns[fb];
                floatx4 u0 = *(const floatx4*)&cns[576 + fb];
                floatx4 u1 = *(const floatx4*)&cns[832 + fb];
                #pragma unroll
                for (int j = 0; j < 4; j++) if (j < cnt) {
                    int rb = base16 + j*16 + cl;
                    float xa = xls[rb], xc = xls[176 + rb];
                    a1[i][j] = bv + u0*xa + u1*xc;
                }
            }
            if (t > 0) {
                #pragma unroll
                for (int kk = 0; kk < 4; kk++)
                    #pragma unroll
                    for (int j = 0; j < 4; j++) if (j < cnt) {
                        half8 bf = *(const half8*)&Sp[(kk>>1)*11264 + (base16 + j*16 + cl)*64
                                                      + (((kk&1)*32 + quad*8) ^ SW(cl))];
                        a1[0][j] = __builtin_amdgcn_mfma_f32_16x16x32_f16(w1f[0][kk], bf, a1[0][j], 0,0,0);
                        a1[1][j] = __builtin_amdgcn_mfma_f32_16x16x32_f16(w1f[1][kk], bf, a1[1][j], 0,0,0);
                    }
            }
            #pragma unroll
            for (int i = 0; i < 2; i++) {
                int fb = (2*w + i)*16 + quad*4;
                #pragma unroll
                for (int j = 0; j < 4; j++) if (j < cnt) {
                    int rl = j*16 + cl;
                    half4v pk;
                    #pragma unroll
                    for (int r = 0; r < 4; r++) {
                        float v = a1[i][j][r]; v = v > 0.f ? v : 0.f;
                        pk[r] = (_Float16)v;
                    }
                    *(half4v*)&H1[rl*256 + (fb ^ SW(cl))] = pk;
                }
            }
            __syncthreads();   // L1 done (also next-chunk staging drained)

            // signal producers one barrier after staging of the LAST chunk drained
            if (c == NCH-2 && t > 0 && tid < 2)
                __hip_atomic_fetch_add(&cons[tid ? f1ix : f0ix], 1,
                                       __ATOMIC_RELAXED, __HIP_MEMORY_SCOPE_AGENT);

            // ---- L2: 256 -> 256 ----
            floatx4 a2[2][4];
            #pragma unroll
            for (int i = 0; i < 2; i++) {
                int fb = (2*w + i)*16 + quad*4;
                floatx4 bv = *(const floatx4*)&cns[256 + fb];
                #pragma unroll
                for (int j = 0; j < 4; j++) if (j < cnt) a2[i][j] = bv;
            }
            #pragma unroll
            for (int kk = 0; kk < 8; kk++)
                #pragma unroll
                for (int j = 0; j < 4; j++) if (j < cnt) {
                    half8 bf = *(const half8*)&H1[(j*16 + cl)*256 + ((kk*32 + quad*8) ^ SW(cl))];
                    a2[0][j] = __builtin_amdgcn_mfma_f32_16x16x32_f16(w2f[0][kk], bf, a2[0][j], 0,0,0);
                    a2[1][j] = __builtin_amdgcn_mfma_f32_16x16x32_f16(w2f[1][kk], bf, a2[1][j], 0,0,0);
                }
            #pragma unroll
            for (int i = 0; i < 2; i++) {
                int fb = (2*w + i)*16 + quad*4;
                #pragma unroll
                for (int j = 0; j < 4; j++) if (j < cnt) {
                    int rl = j*16 + cl;
                    half4v pk;
                    #pragma unroll
                    for (int r = 0; r < 4; r++) {
                        float v = a2[i][j][r]; v = v > 0.f ? v : 0.f;
                        pk[r] = (_Float16)v;
                    }
                    *(half4v*)&H2[rl*256 + (fb ^ SW(cl))] = pk;
                }
            }
            __syncthreads();   // L2 done

            // ---- L3: 256 -> 64, tanh, state -> global (agent-scope store) ----
            {
                int f3 = mt3*16 + quad*4;
                floatx4 bv = *(const floatx4*)&cns[512 + f3];
                floatx4 a3[2];
                #pragma unroll
                for (int jj = 0; jj < 2; jj++) a3[jj] = bv;
                #pragma unroll
                for (int kk = 0; kk < 8; kk++)
                    #pragma unroll
                    for (int jj = 0; jj < 2; jj++) {
                        int j = half*2 + jj;
                        if (j < cnt) {
                            half8 bf = *(const half8*)&H2[(j*16 + cl)*256 + ((kk*32 + quad*8) ^ SW(cl))];
                            a3[jj] = __builtin_amdgcn_mfma_f32_16x16x32_f16(w3f[kk], bf, a3[jj], 0,0,0);
                        }
                    }
                #pragma unroll
                for (int jj = 0; jj < 2; jj++) {
                    int j = half*2 + jj;
                    if (j < cnt) {
                        int grow = r0 + base16 + j*16 + cl;
                        union { _Float16 hh[4]; u64 q; } pk;
                        #pragma unroll
                        for (int r = 0; r < 4; r++) pk.hh[r] = (_Float16)tanhf(a3[jj][r]);
                        AGENT_ST((u64*)(Sg + ((size_t)(((t&1)*5 + n)*8192 + grow))*64 + f3), pk.q);
                    }
                }
            }
            // no barrier: next chunk's L1 writes H1 (disjoint from H2 readers)
        }

        // ---- publish: barrier drains vmcnt(0) for all waves, then flag ----
        __syncthreads();
        if (tid == 0)
            AGENT_ST(&flags[myix], t+1);
    }
}

__global__ __launch_bounds__(512, 2) void scan_kernel(
    const float* __restrict__ x, const float* __restrict__ W1,
    const float* __restrict__ b1, const float* __restrict__ b2, const float* __restrict__ b3,
    const _Float16* __restrict__ w1p, const _Float16* __restrict__ w2p,
    const _Float16* __restrict__ w3p,
    _Float16* __restrict__ Sg, int* flags, int* cons)
{
    extern __shared__ char smem[];
    int b = blockIdx.x;
    int n = b / NB, idx = b % NB;
    int r0 = idx < 2 ? idx*176 : 352 + (idx-2)*160;
    if (idx < 2)
        scan_impl<11>(x, W1, b1, b2, b3, w1p, w2p, w3p, Sg, flags, cons, smem, n, idx, r0);
    else
        scan_impl<10>(x, W1, b1, b2, b3, w1p, w2p, w3p, Sg, flags, cons, smem, n, idx, r0);
}

// ---------------- hpre: relu([x_127, states] @ Wo1 + bo1) ----------------
__global__ __launch_bounds__(512) void hpre_kernel(
    const float* __restrict__ x, const float* __restrict__ Wo1, const float* __restrict__ bo1,
    const _Float16* __restrict__ wo1p, const _Float16* __restrict__ Sg,
    float* __restrict__ hpre)
{
    __shared__ float x5[640];     // [5][128]
    __shared__ float wxo[1280];   // Wo1 rows 0..4
    __shared__ float bo1c[256];
    int tid = threadIdx.x, w = tid >> 6, lane = tid & 63;
    int quad = lane >> 4, cl = lane & 15;
    int r0h = blockIdx.x * 128;

    for (int i = tid; i < 640; i += 512)
        x5[i] = x[(size_t)(r0h + (i & 127))*640 + (i >> 7)*128 + 127];
    for (int i = tid; i < 1280; i += 512) wxo[i] = Wo1[i];
    if (tid < 256) bo1c[tid] = bo1[tid];

    half8 of[2][10];
    #pragma unroll
    for (int i = 0; i < 2; i++) {
        int mt = 2*w + i;
        #pragma unroll
        for (int kk = 0; kk < 10; kk++)
            of[i][kk] = *(const half8*)(wo1p + (size_t)(mt*10 + kk)*512 + lane*8);
    }
    __syncthreads();

    floatx4 acc[2][8];
    #pragma unroll
    for (int i = 0; i < 2; i++) {
        int fb = (2*w + i)*16 + quad*4;
        floatx4 bv = *(const floatx4*)&bo1c[fb];
        #pragma unroll
        for (int nt = 0; nt < 8; nt++) {
            floatx4 a = bv;
            #pragma unroll
            for (int p = 0; p < 5; p++) {
                floatx4 wv = *(const floatx4*)&wxo[p*256 + fb];
                float xv = x5[p*128 + nt*16 + cl];
                a += wv * xv;
            }
            acc[i][nt] = a;
        }
    }
    #pragma unroll
    for (int kk = 0; kk < 10; kk++) {
        int nd = kk >> 1;
        #pragma unroll
        for (int nt = 0; nt < 8; nt++) {
            const _Float16* sp = Sg + ((size_t)((5 + nd)*8192 + r0h + nt*16 + cl))*64
                                    + (kk & 1)*32 + quad*8;   // buf 1 = state(127)
            half8 bf = *(const half8*)sp;
            acc[0][nt] = __builtin_amdgcn_mfma_f32_16x16x32_f16(of[0][kk], bf, acc[0][nt], 0,0,0);
            acc[1][nt] = __builtin_amdgcn_mfma_f32_16x16x32_f16(of[1][kk], bf, acc[1][nt], 0,0,0);
        }
    }
    #pragma unroll
    for (int i = 0; i < 2; i++) {
        int fb = (2*w + i)*16 + quad*4;
        #pragma unroll
        for (int nt = 0; nt < 8; nt++) {
            floatx4 v = acc[i][nt];
            #pragma unroll
            for (int r = 0; r < 4; r++) v[r] = v[r] > 0.f ? v[r] : 0.f;
            *(floatx4*)&hpre[(size_t)(r0h + nt*16 + cl)*256 + fb] = v;
        }
    }
}

// ---------------- BN stats ----------------
__global__ __launch_bounds__(256) void bnstats_kernel(const float* __restrict__ hpre,
                                                      float* __restrict__ sums)
{
    int col = threadIdx.x;
    int r0 = blockIdx.x * 128;
    float s = 0.f, s2 = 0.f;
    for (int r = 0; r < 128; r++) {
        float v = hpre[(size_t)(r0 + r)*256 + col];
        s += v; s2 += v*v;
    }
    atomicAdd(&sums[col], s);
    atomicAdd(&sums[256 + col], s2);
}

// ---------------- normalize + Wo2 + softmax ----------------
__global__ __launch_bounds__(256) void head_kernel(
    const float* __restrict__ hpre, const float* __restrict__ sums,
    const float* __restrict__ gamma, const float* __restrict__ beta,
    const float* __restrict__ Wo2, const float* __restrict__ bo2,
    float* __restrict__ out)
{
    int row  = blockIdx.x * 4 + (threadIdx.x >> 6);
    int lane = threadIdx.x & 63;
    floatx4 h  = *(const floatx4*)&hpre[(size_t)row*256 + lane*4];
    floatx4 sm = *(const floatx4*)&sums[lane*4];
    floatx4 sq = *(const floatx4*)&sums[256 + lane*4];
    floatx4 g  = *(const floatx4*)&gamma[lane*4];
    floatx4 bb = *(const floatx4*)&beta[lane*4];
    float acc[7] = {0.f,0.f,0.f,0.f,0.f,0.f,0.f};
    #pragma unroll
    for (int e = 0; e < 4; e++) {
        float mu  = sm[e] * (1.f/8192.f);
        float var = sq[e] * (1.f/8192.f) - mu*mu;
        float hn  = (h[e] - mu) * rsqrtf(var + 1e-5f) * g[e] + bb[e];
        int colg = lane*4 + e;
        #pragma unroll
        for (int j = 0; j < 7; j++) acc[j] += hn * Wo2[colg*7 + j];
    }
    #pragma unroll
    for (int off = 1; off < 64; off <<= 1) {
        #pragma unroll
        for (int j = 0; j < 7; j++) acc[j] += __shfl_xor(acc[j], off, 64);
    }
    float z[7], m = -1e30f;
    #pragma unroll
    for (int j = 0; j < 7; j++) { z[j] = acc[j] + bo2[j]; m = fmaxf(m, z[j]); }
    float se = 0.f;
    #pragma unroll
    for (int j = 0; j < 7; j++) { z[j] = expf(z[j] - m); se += z[j]; }
    if (lane < 7) out[(size_t)row*7 + lane] = z[lane] / se;
}

extern "C" void kernel_launch(void* const* d_in, const int* in_sizes, int n_in,
                              void* d_out, int out_size, void* d_ws, size_t ws_size,
                              hipStream_t stream)
{
    const float* x    = (const float*)d_in[0];
    const float* W1   = (const float*)d_in[1];
    const float* b1   = (const float*)d_in[2];
    const float* W2   = (const float*)d_in[3];
    const float* b2   = (const float*)d_in[4];
    const float* W3   = (const float*)d_in[5];
    const float* b3   = (const float*)d_in[6];
    const float* Wo1  = (const float*)d_in[7];
    const float* bo1  = (const float*)d_in[8];
    const float* gamma= (const float*)d_in[9];
    const float* beta = (const float*)d_in[10];
    const float* Wo2  = (const float*)d_in[11];
    const float* bo2  = (const float*)d_in[12];
    float* out = (float*)d_out;

    if (ws_size < WS_NEEDED) return;
    char* ws = (char*)d_ws;
    float*     hpre  = (float*)(ws + HPRE_OFF);
    float*     sums  = (float*)(ws + SUM_OFF);
    int*       flags = (int*)(ws + FLAG_OFF);
    int*       cons  = (int*)(ws + CONS_OFF);
    _Float16*  Sg    = (_Float16*)(ws + SG_OFF);
    _Float16*  w1p   = (_Float16*)(ws + PACK_OFF);
    _Float16*  w2p   = w1p + W1P_HALFS;
    _Float16*  w3p   = w2p + W2P_HALFS;
    _Float16*  wo1p  = w3p + W3P_HALFS;

    hipFuncSetAttribute((const void*)scan_kernel,
                        hipFuncAttributeMaxDynamicSharedMemorySize, SMEM_BYTES);

    pack_kernel<<<320, 256, 0, stream>>>(W1, W2, W3, Wo1, w1p, w2p, w3p, wo1p,
                                         sums, flags, cons);
    scan_kernel<<<5*NB, 512, SMEM_BYTES, stream>>>(x, W1, b1, b2, b3,
                                                   w1p, w2p, w3p, Sg, flags, cons);
    hpre_kernel<<<64, 512, 0, stream>>>(x, Wo1, bo1, wo1p, Sg, hpre);
    bnstats_kernel<<<64, 256, 0, stream>>>(hpre, sums);
    head_kernel<<<2048, 256, 0, stream>>>(hpre, sums, gamma, beta, Wo2, bo2, out);
}